// Round 2
// baseline (284.861 us; speedup 1.0000x reference)
//
#include <hip/hip_runtime.h>
#include <hip/hip_bf16.h>

#define IN_F 8192
#define OUT_F 28672
#define RANK 32
#define NGROUPS 128          // IN_F / 64
#define M_TOK 16
#define TCHUNK 16            // K-chunks for lora-t partials
#define TCK (IN_F / TCHUNK)  // 512

typedef __bf16 bf16x8 __attribute__((ext_vector_type(8)));
typedef float  f32x4  __attribute__((ext_vector_type(4)));
typedef int    i32x4  __attribute__((ext_vector_type(4)));

// ---------------------------------------------------------------------------
// Kernel 1: part[c][m*32+r] = sum over k-chunk c of x[m][k] * lora_down[r][k]
// Pure scalar f32 (exact), 16 blocks x 512 threads, deterministic.
// ---------------------------------------------------------------------------
__global__ __launch_bounds__(512) void svdq_tpart(
    const float* __restrict__ x, const float* __restrict__ ld,
    float* __restrict__ part) {
  const int c = blockIdx.x;
  const int i = threadIdx.x;          // 0..511
  const int m = i >> 5, r = i & 31;
  const f32x4* xp = reinterpret_cast<const f32x4*>(x  + (size_t)m * IN_F + c * TCK);
  const f32x4* lp = reinterpret_cast<const f32x4*>(ld + (size_t)r * IN_F + c * TCK);
  float s = 0.f;
#pragma unroll 8
  for (int j = 0; j < TCK / 4; ++j) {
    f32x4 a = xp[j], b = lp[j];
    s += a[0]*b[0] + a[1]*b[1] + a[2]*b[2] + a[3]*b[3];
  }
  part[(size_t)c * (M_TOK * RANK) + i] = s;
}

// ---------------------------------------------------------------------------
// Kernel 2: fused dequant-GEMM + lora-up + bias.
// grid = OUT_F/16 = 1792 blocks x 64 threads (1 wave per 16-col tile)
// ---------------------------------------------------------------------------
__global__ __launch_bounds__(64) void svdq_main(
    const float* __restrict__ x, const int* __restrict__ qw,
    const float* __restrict__ wsc, const float* __restrict__ lu,
    const float* __restrict__ bias, const float* __restrict__ part,
    float* __restrict__ out) {
  const int l   = threadIdx.x;
  const int col = l & 15;
  const int hi  = l >> 4;
  const int o   = blockIdx.x * 16 + col;

  const int*   qrow = qw  + (size_t)o * IN_F + hi * 8;
  const float* xrow = x   + (size_t)col * IN_F + hi * 8;
  const float* srow = wsc + (size_t)o * NGROUPS;

  f32x4 acc = {0.f, 0.f, 0.f, 0.f};

#pragma unroll 1
  for (int g8 = 0; g8 < 16; ++g8) {
    // 8 scales cover k in [g8*512, g8*512+512)
    f32x4 sA = *reinterpret_cast<const f32x4*>(srow + g8 * 8);
    f32x4 sB = *reinterpret_cast<const f32x4*>(srow + g8 * 8 + 4);
#pragma unroll
    for (int kk = 0; kk < 16; ++kk) {
      const int k0 = g8 * 512 + kk * 32;
      i32x4 q0  = *reinterpret_cast<const i32x4*>(qrow + k0);
      i32x4 q1  = *reinterpret_cast<const i32x4*>(qrow + k0 + 4);
      f32x4 xf0 = *reinterpret_cast<const f32x4*>(xrow + k0);
      f32x4 xf1 = *reinterpret_cast<const f32x4*>(xrow + k0 + 4);
      const int   sidx = kk >> 1;                       // compile-time
      const float s = (sidx < 4) ? sA[sidx] : sB[sidx - 4];
      bf16x8 a, b;
#pragma unroll
      for (int j = 0; j < 4; ++j) {
        a[j]     = (__bf16)xf0[j];
        a[j + 4] = (__bf16)xf1[j];
        b[j]     = (__bf16)((float)q0[j] * s);
        b[j + 4] = (__bf16)((float)q1[j] * s);
      }
      acc = __builtin_amdgcn_mfma_f32_16x16x32_bf16(a, b, acc, 0, 0, 0);
    }
  }

  // ---- LoRA epilogue: reduce t partials for this lane's fragment, 1 MFMA ----
  f32x4 t0 = {0.f,0.f,0.f,0.f}, t1 = {0.f,0.f,0.f,0.f};
#pragma unroll
  for (int c = 0; c < TCHUNK; ++c) {
    const f32x4* pc = reinterpret_cast<const f32x4*>(
        part + (size_t)c * (M_TOK * RANK) + col * RANK + hi * 8);
    t0 += pc[0];
    t1 += pc[1];
  }
  f32x4 u0 = *reinterpret_cast<const f32x4*>(lu + (size_t)o * RANK + hi * 8);
  f32x4 u1 = *reinterpret_cast<const f32x4*>(lu + (size_t)o * RANK + hi * 8 + 4);
  bf16x8 ta, lb;
#pragma unroll
  for (int j = 0; j < 4; ++j) {
    ta[j]     = (__bf16)t0[j];
    ta[j + 4] = (__bf16)t1[j];
    lb[j]     = (__bf16)u0[j];
    lb[j + 4] = (__bf16)u1[j];
  }
  acc = __builtin_amdgcn_mfma_f32_16x16x32_bf16(ta, lb, acc, 0, 0, 0);

  const float bv = bias[o];
#pragma unroll
  for (int reg = 0; reg < 4; ++reg) {
    const int m = hi * 4 + reg;
    out[(size_t)m * OUT_F + o] = acc[reg] + bv;
  }
}

extern "C" void kernel_launch(void* const* d_in, const int* in_sizes, int n_in,
                              void* d_out, int out_size, void* d_ws, size_t ws_size,
                              hipStream_t stream) {
  const float* x    = (const float*)d_in[0];
  const int*   qw   = (const int*)d_in[1];
  const float* wsc  = (const float*)d_in[2];
  const float* ld   = (const float*)d_in[3];
  const float* lu   = (const float*)d_in[4];
  const float* bias = (const float*)d_in[5];
  float*       out  = (float*)d_out;

  float* part = (float*)d_ws;   // TCHUNK * 16 * 32 f32 = 32 KB

  svdq_tpart<<<TCHUNK, 512, 0, stream>>>(x, ld, part);
  svdq_main<<<OUT_F / 16, 64, 0, stream>>>(x, qw, wsc, lu, bias, part, out);
}

// Round 3
// 242.113 us; speedup vs baseline: 1.1766x; 1.1766x over previous
//
#include <hip/hip_runtime.h>
#include <hip/hip_bf16.h>

#define IN_F 8192
#define OUT_F 28672
#define RANK 32
#define NGROUPS 128          // IN_F / 64
#define M_TOK 16
#define TCHUNK 16            // K-chunks for lora-t partials
#define TCK (IN_F / TCHUNK)  // 512
#define KSPLIT 4
#define KW (IN_F / KSPLIT)   // 2048 per wave

typedef __bf16 bf16x8 __attribute__((ext_vector_type(8)));
typedef float  f32x4  __attribute__((ext_vector_type(4)));
typedef int    i32x4  __attribute__((ext_vector_type(4)));

// ---------------------------------------------------------------------------
// Kernel 0: cast x (f32) -> bf16 into ws. 16*8192 = 131072 elems.
// ---------------------------------------------------------------------------
__global__ __launch_bounds__(256) void svdq_xcast(
    const float* __restrict__ x, __bf16* __restrict__ xb) {
  const int i = blockIdx.x * 256 + threadIdx.x;   // grid 64 blocks -> i < 16384
  f32x4 a = reinterpret_cast<const f32x4*>(x)[i * 2];
  f32x4 b = reinterpret_cast<const f32x4*>(x)[i * 2 + 1];
  bf16x8 v;
#pragma unroll
  for (int j = 0; j < 4; ++j) { v[j] = (__bf16)a[j]; v[j + 4] = (__bf16)b[j]; }
  reinterpret_cast<bf16x8*>(xb)[i] = v;
}

// ---------------------------------------------------------------------------
// Kernel 1: part[c][m*32+r] = sum over k-chunk c of x[m][k] * lora_down[r][k]
// Pure scalar f32 (exact), 16 blocks x 512 threads, deterministic.
// ---------------------------------------------------------------------------
__global__ __launch_bounds__(512) void svdq_tpart(
    const float* __restrict__ x, const float* __restrict__ ld,
    float* __restrict__ part) {
  const int c = blockIdx.x;
  const int i = threadIdx.x;          // 0..511
  const int m = i >> 5, r = i & 31;
  const f32x4* xp = reinterpret_cast<const f32x4*>(x  + (size_t)m * IN_F + c * TCK);
  const f32x4* lp = reinterpret_cast<const f32x4*>(ld + (size_t)r * IN_F + c * TCK);
  float s = 0.f;
#pragma unroll 8
  for (int j = 0; j < TCK / 4; ++j) {
    f32x4 a = xp[j], b = lp[j];
    s += a[0]*b[0] + a[1]*b[1] + a[2]*b[2] + a[3]*b[3];
  }
  part[(size_t)c * (M_TOK * RANK) + i] = s;
}

// ---------------------------------------------------------------------------
// Kernel 2: fused dequant-GEMM + lora-up + bias, 4-way split-K per block.
// grid = OUT_F/16 = 1792 blocks x 256 threads (4 waves, one 16-col tile)
// ---------------------------------------------------------------------------
__global__ __launch_bounds__(256) void svdq_main(
    const __bf16* __restrict__ xb, const int* __restrict__ qw,
    const float* __restrict__ wsc, const float* __restrict__ lu,
    const float* __restrict__ bias, const float* __restrict__ part,
    float* __restrict__ out) {
  const int w    = threadIdx.x >> 6;   // wave id: K-split slice
  const int lane = threadIdx.x & 63;
  const int col  = lane & 15;
  const int hi   = lane >> 4;
  const int o    = blockIdx.x * 16 + col;

  const int*    qrow = qw  + (size_t)o * IN_F + w * KW + hi * 8;
  const __bf16* xrow = xb  + (size_t)col * IN_F + w * KW + hi * 8;
  const float*  srow = wsc + (size_t)o * NGROUPS + w * (KW / 64);

  f32x4 acc = {0.f, 0.f, 0.f, 0.f};

#pragma unroll 1
  for (int g8 = 0; g8 < KW / 512; ++g8) {
    // 8 scales cover relative k in [g8*512, g8*512+512)
    f32x4 sA = *reinterpret_cast<const f32x4*>(srow + g8 * 8);
    f32x4 sB = *reinterpret_cast<const f32x4*>(srow + g8 * 8 + 4);
#pragma unroll
    for (int kk = 0; kk < 16; ++kk) {
      const int k0 = g8 * 512 + kk * 32;
      i32x4 q0 = *reinterpret_cast<const i32x4*>(qrow + k0);
      i32x4 q1 = *reinterpret_cast<const i32x4*>(qrow + k0 + 4);
      bf16x8 a = *reinterpret_cast<const bf16x8*>(xrow + k0);
      const int   sidx = kk >> 1;                       // compile-time
      const float s = (sidx < 4) ? sA[sidx] : sB[sidx - 4];
      bf16x8 b;
#pragma unroll
      for (int j = 0; j < 4; ++j) {
        b[j]     = (__bf16)((float)q0[j] * s);
        b[j + 4] = (__bf16)((float)q1[j] * s);
      }
      acc = __builtin_amdgcn_mfma_f32_16x16x32_bf16(a, b, acc, 0, 0, 0);
    }
  }

  // ---- split-K reduction in LDS ----
  __shared__ float red[KSPLIT][64][4];
#pragma unroll
  for (int r = 0; r < 4; ++r) red[w][lane][r] = acc[r];
  __syncthreads();
  if (threadIdx.x >= 64) return;

  f32x4 tot = {0.f, 0.f, 0.f, 0.f};
#pragma unroll
  for (int ww = 0; ww < KSPLIT; ++ww) {
    f32x4 v = *reinterpret_cast<const f32x4*>(&red[ww][lane][0]);
    tot += v;
  }

  // ---- LoRA epilogue: reduce t partials for this lane's fragment, 1 MFMA ----
  f32x4 t0 = {0.f,0.f,0.f,0.f}, t1 = {0.f,0.f,0.f,0.f};
#pragma unroll
  for (int c = 0; c < TCHUNK; ++c) {
    const f32x4* pc = reinterpret_cast<const f32x4*>(
        part + (size_t)c * (M_TOK * RANK) + col * RANK + hi * 8);
    t0 += pc[0];
    t1 += pc[1];
  }
  f32x4 u0 = *reinterpret_cast<const f32x4*>(lu + (size_t)o * RANK + hi * 8);
  f32x4 u1 = *reinterpret_cast<const f32x4*>(lu + (size_t)o * RANK + hi * 8 + 4);
  bf16x8 ta, lb;
#pragma unroll
  for (int j = 0; j < 4; ++j) {
    ta[j]     = (__bf16)t0[j];
    ta[j + 4] = (__bf16)t1[j];
    lb[j]     = (__bf16)u0[j];
    lb[j + 4] = (__bf16)u1[j];
  }
  f32x4 lacc = {0.f, 0.f, 0.f, 0.f};
  lacc = __builtin_amdgcn_mfma_f32_16x16x32_bf16(ta, lb, lacc, 0, 0, 0);

  const float bv = bias[o];
#pragma unroll
  for (int reg = 0; reg < 4; ++reg) {
    const int m = hi * 4 + reg;
    out[(size_t)m * OUT_F + o] = tot[reg] + lacc[reg] + bv;
  }
}

extern "C" void kernel_launch(void* const* d_in, const int* in_sizes, int n_in,
                              void* d_out, int out_size, void* d_ws, size_t ws_size,
                              hipStream_t stream) {
  const float* x    = (const float*)d_in[0];
  const int*   qw   = (const int*)d_in[1];
  const float* wsc  = (const float*)d_in[2];
  const float* ld   = (const float*)d_in[3];
  const float* lu   = (const float*)d_in[4];
  const float* bias = (const float*)d_in[5];
  float*       out  = (float*)d_out;

  float*  part = (float*)d_ws;                          // 16*512 f32 = 32 KB
  __bf16* xbf  = (__bf16*)((char*)d_ws + 64 * 1024);    // 256 KB

  svdq_xcast<<<M_TOK * IN_F / (256 * 8), 256, 0, stream>>>(x, xbf);
  svdq_tpart<<<TCHUNK, 512, 0, stream>>>(x, ld, part);
  svdq_main<<<OUT_F / 16, 256, 0, stream>>>(xbf, qw, wsc, lu, bias, part, out);
}